// Round 19
// baseline (211.790 us; speedup 1.0000x reference)
//
#include <hip/hip_runtime.h>
#include <hip/hip_bf16.h>

typedef __hip_bfloat16 bf16;
typedef __attribute__((ext_vector_type(8))) short short8v;          // 8 bf16 (4 VGPRs)
typedef __attribute__((ext_vector_type(8))) unsigned short ushort8v;
typedef __attribute__((ext_vector_type(4))) unsigned short ushort4v;
typedef __attribute__((ext_vector_type(4))) float float4v;

__device__ __forceinline__ float bfu2f(unsigned short u) {
    union { unsigned int i; float f; } v; v.i = ((unsigned int)u) << 16; return v.f;
}
__device__ __forceinline__ unsigned short f2bfu_rn(float x) {
    union { float f; unsigned int i; } u; u.f = x;
    unsigned int r = (u.i + 0x7FFFu + ((u.i >> 16) & 1u)) >> 16;
    return (unsigned short)r;
}

// ---------- cast+transpose weights: W[k][n] fp32 -> Wt[n][k] bf16. grid (4,4,4) ----------
__global__ __launch_bounds__(256) void cast_wt(
    const float* __restrict__ Wq, const float* __restrict__ Wk,
    const float* __restrict__ Wv, const float* __restrict__ Wp,
    unsigned short* __restrict__ wt)
{
    __shared__ unsigned short tile[64][72];
    const float* W = (blockIdx.z == 0) ? Wq : (blockIdx.z == 1) ? Wk
                   : (blockIdx.z == 2) ? Wv : Wp;
    unsigned short* WT = wt + (size_t)blockIdx.z * 65536;
    const int t = threadIdx.x;
    const int k0 = blockIdx.x * 64, n0 = blockIdx.y * 64;
    {
        const int r = t >> 2, cseg = (t & 3) * 16;
        const float* src = W + (size_t)(k0 + r) * 256 + n0 + cseg;
        #pragma unroll
        for (int j = 0; j < 16; ++j) tile[r][cseg + j] = f2bfu_rn(src[j]);
    }
    __syncthreads();
    {
        const int ch = t & 63, lq = t >> 6;
        ushort8v o0, o1;
        #pragma unroll
        for (int i = 0; i < 8; ++i) o0[i] = tile[lq * 16 + i][ch];
        #pragma unroll
        for (int i = 0; i < 8; ++i) o1[i] = tile[lq * 16 + 8 + i][ch];
        unsigned short* dst = WT + (size_t)(n0 + ch) * 256 + k0 + lq * 16;
        *(ushort8v*)(dst)     = o0;
        *(ushort8v*)(dst + 8) = o1;
    }
}

// ---------- MFMA projection core: 16 m-rows x 128 n-cols per wave ----------
__device__ __forceinline__ void proj_core(
    const float* __restrict__ aptr, const unsigned short* __restrict__ Wt,
    int nc0, int m16, int quad, float4v acc[8])
{
    #pragma unroll
    for (int i = 0; i < 8; ++i) acc[i] = (float4v){0.f, 0.f, 0.f, 0.f};
    #pragma unroll
    for (int ks = 0; ks < 8; ++ks) {
        float4 a0 = *(const float4*)(aptr + ks * 32);
        float4 a1 = *(const float4*)(aptr + ks * 32 + 4);
        short8v af;
        af[0] = (short)f2bfu_rn(a0.x); af[1] = (short)f2bfu_rn(a0.y);
        af[2] = (short)f2bfu_rn(a0.z); af[3] = (short)f2bfu_rn(a0.w);
        af[4] = (short)f2bfu_rn(a1.x); af[5] = (short)f2bfu_rn(a1.y);
        af[6] = (short)f2bfu_rn(a1.z); af[7] = (short)f2bfu_rn(a1.w);
        #pragma unroll
        for (int i = 0; i < 8; ++i) {
            short8v bfr = *(const short8v*)(Wt + (size_t)(nc0 + i * 16 + m16) * 256 + ks * 32 + quad * 8);
            acc[i] = __builtin_amdgcn_mfma_f32_16x16x32_bf16(af, bfr, acc[i], 0, 0, 0);
        }
    }
}

// ---------- fused q/k/v projections. grid 691: [0,19) q, [19,355) k, [355,691) v ----------
__global__ __launch_bounds__(256) void proj_all(
    const float* __restrict__ q, const float* __restrict__ k, const float* __restrict__ v,
    const unsigned short* __restrict__ wt,
    unsigned short* __restrict__ qb, unsigned short* __restrict__ kb,
    unsigned short* __restrict__ vt)
{
    const int t = threadIdx.x;
    const int wave = t >> 6, lane = t & 63;
    const int m16 = lane & 15, quad = lane >> 4;
    const int msub = (wave & 1) * 16;
    const int nc0 = (wave >> 1) * 128;
    const int bx = blockIdx.x;

    float4v acc[8];
    if (bx < 19) {                       // ---- query -> qb (row-major), M=600
        const int m0 = bx * 32;
        const int arow = min(m0 + msub + m16, 599);
        proj_core(q + (size_t)arow * 256 + quad * 8, wt, nc0, m16, quad, acc);
        #pragma unroll
        for (int i = 0; i < 8; ++i)
            #pragma unroll
            for (int r = 0; r < 4; ++r) {
                int m = m0 + msub + quad * 4 + r;
                if (m < 600)
                    qb[(size_t)m * 256 + nc0 + i * 16 + m16] = f2bfu_rn(acc[i][r]);
            }
    } else if (bx < 355) {               // ---- key -> kb (row-major), M=10752
        const int m0 = (bx - 19) * 32;
        proj_core(k + (size_t)(m0 + msub + m16) * 256 + quad * 8, wt + 65536, nc0, m16, quad, acc);
        #pragma unroll
        for (int i = 0; i < 8; ++i)
            #pragma unroll
            for (int r = 0; r < 4; ++r) {
                int m = m0 + msub + quad * 4 + r;
                kb[(size_t)m * 256 + nc0 + i * 16 + m16] = f2bfu_rn(acc[i][r]);
            }
    } else {                             // ---- value -> vt (transposed), M=10752
        const int m0 = (bx - 355) * 32;
        proj_core(v + (size_t)(m0 + msub + m16) * 256 + quad * 8, wt + 131072, nc0, m16, quad, acc);
        const int bb = (m0 >= 5376) ? 1 : 0;
        const int lcol = m0 - bb * 5376 + msub + quad * 4;
        #pragma unroll
        for (int i = 0; i < 8; ++i) {
            const int ch = nc0 + i * 16 + m16;
            ushort4v p;
            #pragma unroll
            for (int r = 0; r < 4; ++r) p[r] = f2bfu_rn(acc[i][r]);
            *(ushort4v*)(vt + (size_t)(bb * 256 + ch) * 5376 + lcol) = p;
        }
    }
}

// ---------- fused QK + mask-FC + softmax + PV, 2 l-chunks per block. grid 800 (798 used) ----------
// XCD stripe swizzle: block i -> XCD i&7, g = (i&7)*100 + (i>>3); zg-major decode so each
// XCD owns a contiguous l-stripe (k+vt working set ~1.4 MB resident in its L2).
// Block = (n-tile 16, b, z-group of 2 chunks x 128 l). Wave = head. PV acc + sum(exp)
// carry across both chunks -> xbp/Sp have 21 planes. NT stores for all streamed outputs.
__global__ __launch_bounds__(512) void attn_fused(
    const unsigned short* __restrict__ qb, const unsigned short* __restrict__ kb,
    const unsigned short* __restrict__ vt,
    const float* __restrict__ W1, const float* __restrict__ b1,
    const float* __restrict__ W2, const float* __restrict__ b2,
    const float* __restrict__ W3, const float* __restrict__ b3,
    const float* __restrict__ Wm, const float* __restrict__ bmp,
    float* __restrict__ f1dot, float* __restrict__ gf,
    float* __restrict__ xbp, float* __restrict__ Sp)
{
    const int STR = 134;                            // probs row stride (shorts)
    __shared__ unsigned short probs[8][16 * 134];   // 34,304 B
    __shared__ float wfc[64], bfc[8], wmf[8];
    __shared__ float bmsS;

    const int i0 = blockIdx.x;
    const int g = (i0 & 7) * 100 + (i0 >> 3);
    if (g >= 798) return;
    const int zg = g / 38;              // 0..20 (contiguous stripe per XCD)
    const int rem = g % 38;
    const int b = rem / 19;
    const int n0 = (rem % 19) * 16;

    const int t = threadIdx.x;
    const int wave = t >> 6, lane = t & 63;
    const int h = wave;
    const int m16 = lane & 15, quad = lane >> 4;
    const float scale = 0.17677669529663687f;   // 1/sqrt(32)

    // FC weights: both chunks of a z-group are in the same level (boundaries 32/40 even)
    {
        const int zz0 = zg * 2;
        const float* Wsel; const float* bsel; int wmoff;
        if (zz0 < 32)      { Wsel = W1; bsel = b1; wmoff = 0; }
        else if (zz0 < 40) { Wsel = W2; bsel = b2; wmoff = 8; }
        else               { Wsel = W3; bsel = b3; wmoff = 16; }
        if (t < 64) wfc[t] = Wsel[t];
        if (t < 8)  { bfc[t] = bsel[t]; wmf[t] = Wm[wmoff + t]; }
        if (t == 0) bmsS = bmp[0];
    }

    const unsigned short* qp = qb + (size_t)(b * 300 + min(n0 + m16, 299)) * 256 + h * 32 + quad * 8;
    const short8v qfrag = *(const short8v*)qp;

    const unsigned short* kbase = kb + (size_t)(b * 5376) * 256 + h * 32 + quad * 8;
    const unsigned short* vt0 = vt + (size_t)(b * 256 + h * 32 + m16) * 5376;
    const unsigned short* vt1 = vt0 + (size_t)16 * 5376;
    unsigned short* pw = &probs[wave][0];

    float4v c0 = {0.f, 0.f, 0.f, 0.f};
    float4v c1 = {0.f, 0.f, 0.f, 0.f};
    float sm = 0.f;

    for (int cc = 0; cc < 2; ++cc) {
        const int zz = zg * 2 + cc;
        const int lc = zz * 128;
        if (cc) __syncthreads();   // all FC reads of previous chunk done before overwrite

        // ---- QK: 8 tiles of 16 l. A = k (m=l), B = q (n=n). C: row=l, col=n.
        #pragma unroll
        for (int i = 0; i < 8; ++i) {
            const int lcol = lc + i * 16 + m16;
            short8v kf = *(const short8v*)(kbase + (size_t)lcol * 256);
            float4v c = {0.f, 0.f, 0.f, 0.f};
            c = __builtin_amdgcn_mfma_f32_16x16x32_bf16(kf, qfrag, c, 0, 0, 0);
            ushort4v pk;
            #pragma unroll
            for (int r = 0; r < 4; ++r) pk[r] = f2bfu_rn(c[r] * scale);
            *(ushort4v*)(pw + m16 * STR + i * 16 + quad * 4) = pk;
        }
        __syncthreads();

        // ---- FC phase: thread -> (n = t>>5, 4 l at lt*4). Reads all 8 heads from LDS.
        {
            const int n = t >> 5, lt = t & 31;
            const int nn = n0 + n;
            if (nn < 300) {
                ushort4v u[8];
                #pragma unroll
                for (int hp = 0; hp < 8; ++hp)
                    u[hp] = *(const ushort4v*)(&probs[hp][0] + n * STR + lt * 4);
                float4v o;
                #pragma unroll
                for (int j = 0; j < 4; ++j) {
                    float acc = (zz < 32) ? bmsS : 0.f;
                    #pragma unroll
                    for (int hh = 0; hh < 8; ++hh) {
                        float s = bfc[hh];
                        #pragma unroll
                        for (int hp = 0; hp < 8; ++hp) s += bfu2f(u[hp][j]) * wfc[hp * 8 + hh];
                        acc += fmaxf(s, 0.f) * wmf[hh];
                    }
                    o[j] = acc;
                }
                if (zz < 32) {
                    __builtin_nontemporal_store(o, (float4v*)(f1dot + (size_t)(b * 300 + nn) * 4096 + lc + lt * 4));
                } else {
                    const int cell = lc - 4096 + lt * 4;   // 0..1279 (g2 then g3)
                    __builtin_nontemporal_store(o, (float4v*)(gf + (size_t)(b * 300 + nn) * 1280 + cell));
                }
            }
        }

        // ---- PV: 4 K-steps of 32 l. A[m=n=m16][k=l], exp on read from own wave region.
        #pragma unroll
        for (int step = 0; step < 4; ++step) {
            const int lloc = step * 32 + quad * 8;
            ushort8v ua = *(const ushort8v*)(pw + m16 * STR + lloc);
            short8v af;
            #pragma unroll
            for (int j = 0; j < 8; ++j) {
                float e = __expf(bfu2f(ua[j]));
                sm += e;
                af[j] = (short)f2bfu_rn(e);
            }
            const int lg = lc + lloc;
            short8v b0 = *(const short8v*)(vt0 + lg);
            short8v b1v = *(const short8v*)(vt1 + lg);
            c0 = __builtin_amdgcn_mfma_f32_16x16x32_bf16(af, b0, c0, 0, 0, 0);
            c1 = __builtin_amdgcn_mfma_f32_16x16x32_bf16(af, b1v, c1, 0, 0, 0);
        }
    }

    // per-wave direct output: lane holds C[n=quad*4+r][d=m16] (c0) and d+16 (c1)
    {
        float* xplane = xbp + (size_t)zg * 153600;
        #pragma unroll
        for (int r = 0; r < 4; ++r) {
            const int nn = n0 + quad * 4 + r;
            if (nn < 300) {
                float* o = xplane + (size_t)(b * 300 + nn) * 256 + h * 32 + m16;
                __builtin_nontemporal_store(c0[r], o);
                __builtin_nontemporal_store(c1[r], o + 16);
            }
        }
        sm += __shfl_xor(sm, 16);
        sm += __shfl_xor(sm, 32);
        if (lane < 16) {
            const int nn = n0 + lane;
            if (nn < 300)
                __builtin_nontemporal_store(sm, Sp + (size_t)zg * 4800 + (size_t)(b * 300 + nn) * 8 + h);
        }
    }
}

// ---------- mask bilinear + x-combine, merged. grid (600,3), 256 thr ----------
// y=0,1: mask pixel halves from f1dot+gf. y=2: combine 21 xbp planes + 1/S -> xb.
__global__ __launch_bounds__(256) void mask_combine(
    const float* __restrict__ f1dot, const float* __restrict__ gf,
    const float* __restrict__ xbp, const float* __restrict__ Sp,
    float* __restrict__ xb, float* __restrict__ out)
{
    const int t  = threadIdx.x;
    const int bn = blockIdx.x;
    const int ph = blockIdx.y;

    if (ph == 2) {   // ---- combine: m = bn
        __shared__ float Sinv[8];
        if (t < 8) {
            float S = 0.f;
            #pragma unroll 7
            for (int z = 0; z < 21; ++z) S += Sp[(size_t)z * 4800 + (size_t)bn * 8 + t];
            Sinv[t] = 1.0f / S;
        }
        __syncthreads();
        float acc = 0.f;
        const float* p = xbp + (size_t)bn * 256 + t;
        #pragma unroll 7
        for (int z = 0; z < 21; ++z) acc += p[(size_t)z * 153600];
        xb[(size_t)bn * 256 + t] = acc * Sinv[t >> 5];
        return;
    }

    __shared__ float gs[1280];          // g2 = gs[0..1024), g3 = gs[1024..1280)
    {
        const float4* src = (const float4*)(gf + (size_t)bn * 1280);
        ((float4*)gs)[t] = src[t];
        if (t < 64) ((float4*)gs)[256 + t] = src[256 + t];
    }
    __syncthreads();

    const int p0 = ph * 2048 + t * 8;
    float f[8];
    *(float4*)&f[0] = *(const float4*)(f1dot + (size_t)bn * 4096 + p0);
    *(float4*)&f[4] = *(const float4*)(f1dot + (size_t)bn * 4096 + p0 + 4);

    float res[8];
    #pragma unroll
    for (int pp = 0; pp < 8; ++pp) {
        const int p = p0 + pp;
        const int Y = p >> 6, X = p & 63;
        float acc = f[pp];
        {   // g2 bilinear 32 -> 64
            float ry = fminf(fmaxf(0.5f * Y - 0.25f, 0.f), 31.f);
            float rx = fminf(fmaxf(0.5f * X - 0.25f, 0.f), 31.f);
            int y0 = (int)ry, x0 = (int)rx;
            int y1 = min(y0 + 1, 31), x1 = min(x0 + 1, 31);
            float wy = ry - (float)y0, wx = rx - (float)x0;
            acc += (gs[y0 * 32 + x0] * (1.f - wx) + gs[y0 * 32 + x1] * wx) * (1.f - wy)
                 + (gs[y1 * 32 + x0] * (1.f - wx) + gs[y1 * 32 + x1] * wx) * wy;
        }
        {   // g3 bilinear 16 -> 64
            float ry = fminf(fmaxf(0.25f * Y - 0.375f, 0.f), 15.f);
            float rx = fminf(fmaxf(0.25f * X - 0.375f, 0.f), 15.f);
            int y0 = (int)ry, x0 = (int)rx;
            int y1 = min(y0 + 1, 15), x1 = min(x0 + 1, 15);
            float wy = ry - (float)y0, wx = rx - (float)x0;
            acc += (gs[1024 + y0 * 16 + x0] * (1.f - wx) + gs[1024 + y0 * 16 + x1] * wx) * (1.f - wy)
                 + (gs[1024 + y1 * 16 + x0] * (1.f - wx) + gs[1024 + y1 * 16 + x1] * wx) * wy;
        }
        res[pp] = fmaxf(acc, 0.f);
    }
    float* o = out + 153600 + (size_t)bn * 4096 + p0;
    *(float4*)(o)     = *(float4*)&res[0];
    *(float4*)(o + 4) = *(float4*)&res[4];
}

// ---------- output projection: out = xb @ Wp + bp. grid 19 ----------
__global__ __launch_bounds__(256) void proj_out(
    const float* __restrict__ xb, const unsigned short* __restrict__ Wtp,
    const float* __restrict__ bp, float* __restrict__ out)
{
    const int t = threadIdx.x;
    const int wave = t >> 6, lane = t & 63;
    const int m16 = lane & 15, quad = lane >> 4;
    const int msub = (wave & 1) * 16;
    const int nc0 = (wave >> 1) * 128;
    const int m0 = blockIdx.x * 32;

    const int arow = min(m0 + msub + m16, 599);
    float4v acc[8];
    proj_core(xb + (size_t)arow * 256 + quad * 8, Wtp, nc0, m16, quad, acc);

    #pragma unroll
    for (int i = 0; i < 8; ++i) {
        const float bv = bp[nc0 + i * 16 + m16];
        #pragma unroll
        for (int r = 0; r < 4; ++r) {
            int m = m0 + msub + quad * 4 + r;
            if (m < 600)
                out[(size_t)m * 256 + nc0 + i * 16 + m16] = acc[i][r] + bv;
        }
    }
}

// ---------- launch ----------
extern "C" void kernel_launch(void* const* d_in, const int* in_sizes, int n_in,
                              void* d_out, int out_size, void* d_ws, size_t ws_size,
                              hipStream_t stream) {
    const float* query = (const float*)d_in[0];
    const float* key   = (const float*)d_in[1];
    const float* value = (const float*)d_in[2];
    const float* Wq = (const float*)d_in[5];
    const float* Wk = (const float*)d_in[6];
    const float* Wv = (const float*)d_in[7];
    const float* Wp = (const float*)d_in[8];
    const float* bp = (const float*)d_in[9];
    const float* W1 = (const float*)d_in[10];
    const float* b1 = (const float*)d_in[11];
    const float* W2 = (const float*)d_in[12];
    const float* b2 = (const float*)d_in[13];
    const float* W3 = (const float*)d_in[14];
    const float* b3 = (const float*)d_in[15];
    const float* Wm = (const float*)d_in[16];
    const float* bm = (const float*)d_in[17];
    float* out = (float*)d_out;

    char* ws = (char*)d_ws;
    unsigned short* wt = (unsigned short*)(ws);       // 4*65536 bf16 = 524,288 B
    bf16*  qb    = (bf16*) (ws + 524288);             // 600*256 bf16      =    307,200 B
    bf16*  kb    = (bf16*) (ws + 831488);             // 10752*256 bf16    =  5,505,024 B
    bf16*  vt    = (bf16*) (ws + 6336512);            // 512*5376 bf16     =  5,505,024 B
    float* f1dot = (float*)(ws + 11841536);           // 600*4096 fp32     =  9,830,400 B
    float* gf    = (float*)(ws + 21671936);           // 600*1280 fp32     =  3,072,000 B
    float* xbp   = (float*)(ws + 24743936);           // 21*600*256 fp32   = 12,902,400 B
    float* Sp    = (float*)(ws + 37646336);           // 21*4800 fp32      =    403,200 B
    float* xb    = (float*)(ws + 38049536);           // 600*256 fp32      =    614,400 B

    cast_wt<<<dim3(4, 4, 4), 256, 0, stream>>>(Wq, Wk, Wv, Wp, wt);

    proj_all<<<691, 256, 0, stream>>>(query, key, value, wt,
        (unsigned short*)qb, (unsigned short*)kb, (unsigned short*)vt);

    attn_fused<<<800, 512, 0, stream>>>(
        (const unsigned short*)qb, (const unsigned short*)kb, (const unsigned short*)vt,
        W1, b1, W2, b2, W3, b3, Wm, bm,
        f1dot, gf, xbp, Sp);

    mask_combine<<<dim3(600, 3), 256, 0, stream>>>(f1dot, gf, xbp, Sp, xb, out);

    proj_out<<<19, 256, 0, stream>>>(xb, (const unsigned short*)wt + 196608, bp, out);
}

// Round 20
// 204.617 us; speedup vs baseline: 1.0351x; 1.0351x over previous
//
#include <hip/hip_runtime.h>
#include <hip/hip_bf16.h>

typedef __hip_bfloat16 bf16;
typedef __attribute__((ext_vector_type(8))) short short8v;          // 8 bf16 (4 VGPRs)
typedef __attribute__((ext_vector_type(8))) unsigned short ushort8v;
typedef __attribute__((ext_vector_type(4))) unsigned short ushort4v;
typedef __attribute__((ext_vector_type(4))) float float4v;

__device__ __forceinline__ float bfu2f(unsigned short u) {
    union { unsigned int i; float f; } v; v.i = ((unsigned int)u) << 16; return v.f;
}
__device__ __forceinline__ unsigned short f2bfu_rn(float x) {
    union { float f; unsigned int i; } u; u.f = x;
    unsigned int r = (u.i + 0x7FFFu + ((u.i >> 16) & 1u)) >> 16;
    return (unsigned short)r;
}

// ---------- cast+transpose weights: W[k][n] fp32 -> Wt[n][k] bf16. grid (4,4,4) ----------
__global__ __launch_bounds__(256) void cast_wt(
    const float* __restrict__ Wq, const float* __restrict__ Wk,
    const float* __restrict__ Wv, const float* __restrict__ Wp,
    unsigned short* __restrict__ wt)
{
    __shared__ unsigned short tile[64][72];
    const float* W = (blockIdx.z == 0) ? Wq : (blockIdx.z == 1) ? Wk
                   : (blockIdx.z == 2) ? Wv : Wp;
    unsigned short* WT = wt + (size_t)blockIdx.z * 65536;
    const int t = threadIdx.x;
    const int k0 = blockIdx.x * 64, n0 = blockIdx.y * 64;
    {
        const int r = t >> 2, cseg = (t & 3) * 16;
        const float* src = W + (size_t)(k0 + r) * 256 + n0 + cseg;
        #pragma unroll
        for (int j = 0; j < 16; ++j) tile[r][cseg + j] = f2bfu_rn(src[j]);
    }
    __syncthreads();
    {
        const int ch = t & 63, lq = t >> 6;
        ushort8v o0, o1;
        #pragma unroll
        for (int i = 0; i < 8; ++i) o0[i] = tile[lq * 16 + i][ch];
        #pragma unroll
        for (int i = 0; i < 8; ++i) o1[i] = tile[lq * 16 + 8 + i][ch];
        unsigned short* dst = WT + (size_t)(n0 + ch) * 256 + k0 + lq * 16;
        *(ushort8v*)(dst)     = o0;
        *(ushort8v*)(dst + 8) = o1;
    }
}

// ---------- MFMA projection core: 16 m-rows x 64 n-cols per wave (4 tiles) ----------
__device__ __forceinline__ void proj_core4(
    const float* __restrict__ aptr, const unsigned short* __restrict__ Wt,
    int nc0, int m16, int quad, float4v acc[4])
{
    #pragma unroll
    for (int i = 0; i < 4; ++i) acc[i] = (float4v){0.f, 0.f, 0.f, 0.f};
    #pragma unroll
    for (int ks = 0; ks < 8; ++ks) {
        float4 a0 = *(const float4*)(aptr + ks * 32);
        float4 a1 = *(const float4*)(aptr + ks * 32 + 4);
        short8v af;
        af[0] = (short)f2bfu_rn(a0.x); af[1] = (short)f2bfu_rn(a0.y);
        af[2] = (short)f2bfu_rn(a0.z); af[3] = (short)f2bfu_rn(a0.w);
        af[4] = (short)f2bfu_rn(a1.x); af[5] = (short)f2bfu_rn(a1.y);
        af[6] = (short)f2bfu_rn(a1.z); af[7] = (short)f2bfu_rn(a1.w);
        #pragma unroll
        for (int i = 0; i < 4; ++i) {
            short8v bfr = *(const short8v*)(Wt + (size_t)(nc0 + i * 16 + m16) * 256 + ks * 32 + quad * 8);
            acc[i] = __builtin_amdgcn_mfma_f32_16x16x32_bf16(af, bfr, acc[i], 0, 0, 0);
        }
    }
}

// ---------- fused q/k/v projections, n-split x2. grid 1382: [0,38) q, [38,710) k, [710,1382) v ----------
__global__ __launch_bounds__(256) void proj_all(
    const float* __restrict__ q, const float* __restrict__ k, const float* __restrict__ v,
    const unsigned short* __restrict__ wt,
    unsigned short* __restrict__ qb, unsigned short* __restrict__ kb,
    unsigned short* __restrict__ vt)
{
    const int t = threadIdx.x;
    const int wave = t >> 6, lane = t & 63;
    const int m16 = lane & 15, quad = lane >> 4;
    const int msub = (wave & 1) * 16;
    const int bx = blockIdx.x;

    float4v acc[4];
    if (bx < 38) {                       // ---- query -> qb (row-major), M=600
        const int m0 = (bx >> 1) * 32;
        const int nc0 = (bx & 1) * 128 + (wave >> 1) * 64;
        const int arow = min(m0 + msub + m16, 599);
        proj_core4(q + (size_t)arow * 256 + quad * 8, wt, nc0, m16, quad, acc);
        #pragma unroll
        for (int i = 0; i < 4; ++i)
            #pragma unroll
            for (int r = 0; r < 4; ++r) {
                int m = m0 + msub + quad * 4 + r;
                if (m < 600)
                    qb[(size_t)m * 256 + nc0 + i * 16 + m16] = f2bfu_rn(acc[i][r]);
            }
    } else if (bx < 710) {               // ---- key -> kb (row-major), M=10752
        const int g = bx - 38;
        const int m0 = (g >> 1) * 32;
        const int nc0 = (g & 1) * 128 + (wave >> 1) * 64;
        proj_core4(k + (size_t)(m0 + msub + m16) * 256 + quad * 8, wt + 65536, nc0, m16, quad, acc);
        #pragma unroll
        for (int i = 0; i < 4; ++i)
            #pragma unroll
            for (int r = 0; r < 4; ++r) {
                int m = m0 + msub + quad * 4 + r;
                kb[(size_t)m * 256 + nc0 + i * 16 + m16] = f2bfu_rn(acc[i][r]);
            }
    } else {                             // ---- value -> vt (transposed), M=10752
        const int g = bx - 710;
        const int m0 = (g >> 1) * 32;
        const int nc0 = (g & 1) * 128 + (wave >> 1) * 64;
        proj_core4(v + (size_t)(m0 + msub + m16) * 256 + quad * 8, wt + 131072, nc0, m16, quad, acc);
        const int bb = (m0 >= 5376) ? 1 : 0;
        const int lcol = m0 - bb * 5376 + msub + quad * 4;
        #pragma unroll
        for (int i = 0; i < 4; ++i) {
            const int ch = nc0 + i * 16 + m16;
            ushort4v p;
            #pragma unroll
            for (int r = 0; r < 4; ++r) p[r] = f2bfu_rn(acc[i][r]);
            *(ushort4v*)(vt + (size_t)(bb * 256 + ch) * 5376 + lcol) = p;
        }
    }
}

// ---------- fused QK + mask-FC + softmax + PV. grid 1600 (1596 used), 512 thr ----------
// Round-18 config: 1 l-chunk of 128 per block, XCD zz-major stripe, NT streamed stores.
__global__ __launch_bounds__(512) void attn_fused(
    const unsigned short* __restrict__ qb, const unsigned short* __restrict__ kb,
    const unsigned short* __restrict__ vt,
    const float* __restrict__ W1, const float* __restrict__ b1,
    const float* __restrict__ W2, const float* __restrict__ b2,
    const float* __restrict__ W3, const float* __restrict__ b3,
    const float* __restrict__ Wm, const float* __restrict__ bmp,
    float* __restrict__ f1dot, float* __restrict__ gf,
    float* __restrict__ xbp, float* __restrict__ Sp)
{
    const int STR = 134;                            // probs row stride (shorts)
    __shared__ unsigned short probs[8][16 * 134];   // 34,304 B
    __shared__ float wfc[64], bfc[8], wmf[8];
    __shared__ float bmsS;

    const int i0 = blockIdx.x;
    const int g = (i0 & 7) * 200 + (i0 >> 3);
    if (g >= 1596) return;
    const int zz = g / 38;              // 0..41 (contiguous stripe per XCD)
    const int rem = g % 38;
    const int b = rem / 19;
    const int n0 = (rem % 19) * 16;

    const int t = threadIdx.x;
    const int wave = t >> 6, lane = t & 63;
    const int h = wave;
    const int m16 = lane & 15, quad = lane >> 4;
    const int lc = zz * 128;
    const float scale = 0.17677669529663687f;   // 1/sqrt(32)

    {
        const float* Wsel; const float* bsel; int wmoff;
        if (zz < 32)      { Wsel = W1; bsel = b1; wmoff = 0; }
        else if (zz < 40) { Wsel = W2; bsel = b2; wmoff = 8; }
        else              { Wsel = W3; bsel = b3; wmoff = 16; }
        if (t < 64) wfc[t] = Wsel[t];
        if (t < 8)  { bfc[t] = bsel[t]; wmf[t] = Wm[wmoff + t]; }
        if (t == 0) bmsS = bmp[0];
    }

    const unsigned short* qp = qb + (size_t)(b * 300 + min(n0 + m16, 299)) * 256 + h * 32 + quad * 8;
    const short8v qfrag = *(const short8v*)qp;

    const unsigned short* kbase = kb + (size_t)(b * 5376) * 256 + h * 32 + quad * 8;
    const unsigned short* vt0 = vt + (size_t)(b * 256 + h * 32 + m16) * 5376;
    const unsigned short* vt1 = vt0 + (size_t)16 * 5376;
    unsigned short* pw = &probs[wave][0];

    // ---- QK: 8 tiles of 16 l. A = k (m=l), B = q (n=n). C: row=l, col=n.
    #pragma unroll
    for (int i = 0; i < 8; ++i) {
        const int lcol = lc + i * 16 + m16;
        short8v kf = *(const short8v*)(kbase + (size_t)lcol * 256);
        float4v c = {0.f, 0.f, 0.f, 0.f};
        c = __builtin_amdgcn_mfma_f32_16x16x32_bf16(kf, qfrag, c, 0, 0, 0);
        ushort4v pk;
        #pragma unroll
        for (int r = 0; r < 4; ++r) pk[r] = f2bfu_rn(c[r] * scale);
        *(ushort4v*)(pw + m16 * STR + i * 16 + quad * 4) = pk;
    }
    __syncthreads();

    // ---- FC phase: thread -> (n = t>>5, 4 l at lt*4). Reads all 8 heads from LDS.
    {
        const int n = t >> 5, lt = t & 31;
        const int nn = n0 + n;
        if (nn < 300) {
            ushort4v u[8];
            #pragma unroll
            for (int hp = 0; hp < 8; ++hp)
                u[hp] = *(const ushort4v*)(&probs[hp][0] + n * STR + lt * 4);
            float4v o;
            #pragma unroll
            for (int j = 0; j < 4; ++j) {
                float acc = (zz < 32) ? bmsS : 0.f;
                #pragma unroll
                for (int hh = 0; hh < 8; ++hh) {
                    float s = bfc[hh];
                    #pragma unroll
                    for (int hp = 0; hp < 8; ++hp) s += bfu2f(u[hp][j]) * wfc[hp * 8 + hh];
                    acc += fmaxf(s, 0.f) * wmf[hh];
                }
                o[j] = acc;
            }
            if (zz < 32) {
                __builtin_nontemporal_store(o, (float4v*)(f1dot + (size_t)(b * 300 + nn) * 4096 + lc + lt * 4));
            } else {
                const int cell = lc - 4096 + lt * 4;   // 0..1279 (g2 then g3)
                __builtin_nontemporal_store(o, (float4v*)(gf + (size_t)(b * 300 + nn) * 1280 + cell));
            }
        }
    }

    // ---- PV: 4 K-steps of 32 l. A[m=n=m16][k=l], exp on read from own wave region.
    float4v c0 = {0.f, 0.f, 0.f, 0.f};
    float4v c1 = {0.f, 0.f, 0.f, 0.f};
    float sm = 0.f;
    #pragma unroll
    for (int step = 0; step < 4; ++step) {
        const int lloc = step * 32 + quad * 8;
        ushort8v ua = *(const ushort8v*)(pw + m16 * STR + lloc);
        short8v af;
        #pragma unroll
        for (int j = 0; j < 8; ++j) {
            float e = __expf(bfu2f(ua[j]));
            sm += e;
            af[j] = (short)f2bfu_rn(e);
        }
        const int lg = lc + lloc;
        short8v b0 = *(const short8v*)(vt0 + lg);
        short8v b1v = *(const short8v*)(vt1 + lg);
        c0 = __builtin_amdgcn_mfma_f32_16x16x32_bf16(af, b0, c0, 0, 0, 0);
        c1 = __builtin_amdgcn_mfma_f32_16x16x32_bf16(af, b1v, c1, 0, 0, 0);
    }

    // per-wave direct output: lane holds C[n=quad*4+r][d=m16] (c0) and d+16 (c1)
    {
        float* xplane = xbp + (size_t)zz * 153600;
        #pragma unroll
        for (int r = 0; r < 4; ++r) {
            const int nn = n0 + quad * 4 + r;
            if (nn < 300) {
                float* o = xplane + (size_t)(b * 300 + nn) * 256 + h * 32 + m16;
                __builtin_nontemporal_store(c0[r], o);
                __builtin_nontemporal_store(c1[r], o + 16);
            }
        }
        sm += __shfl_xor(sm, 16);
        sm += __shfl_xor(sm, 32);
        if (lane < 16) {
            const int nn = n0 + lane;
            if (nn < 300)
                __builtin_nontemporal_store(sm, Sp + (size_t)zz * 4800 + (size_t)(b * 300 + nn) * 8 + h);
        }
    }
}

// ---------- mask bilinear + x-combine, merged. grid (600,3), 256 thr ----------
__global__ __launch_bounds__(256) void mask_combine(
    const float* __restrict__ f1dot, const float* __restrict__ gf,
    const float* __restrict__ xbp, const float* __restrict__ Sp,
    float* __restrict__ xb, float* __restrict__ out)
{
    const int t  = threadIdx.x;
    const int bn = blockIdx.x;
    const int ph = blockIdx.y;

    if (ph == 2) {   // ---- combine: m = bn
        __shared__ float Sinv[8];
        if (t < 8) {
            float S = 0.f;
            #pragma unroll 6
            for (int z = 0; z < 42; ++z) S += Sp[(size_t)z * 4800 + (size_t)bn * 8 + t];
            Sinv[t] = 1.0f / S;
        }
        __syncthreads();
        float acc = 0.f;
        const float* p = xbp + (size_t)bn * 256 + t;
        #pragma unroll 6
        for (int z = 0; z < 42; ++z)
            acc += __builtin_nontemporal_load(p + (size_t)z * 153600);
        xb[(size_t)bn * 256 + t] = acc * Sinv[t >> 5];
        return;
    }

    __shared__ float gs[1280];          // g2 = gs[0..1024), g3 = gs[1024..1280)
    {
        const float4* src = (const float4*)(gf + (size_t)bn * 1280);
        ((float4*)gs)[t] = src[t];
        if (t < 64) ((float4*)gs)[256 + t] = src[256 + t];
    }
    __syncthreads();

    const int p0 = ph * 2048 + t * 8;
    float f[8];
    {
        const float4v* fp = (const float4v*)(f1dot + (size_t)bn * 4096 + p0);
        float4v f0 = __builtin_nontemporal_load(fp);
        float4v f1 = __builtin_nontemporal_load(fp + 1);
        f[0] = f0[0]; f[1] = f0[1]; f[2] = f0[2]; f[3] = f0[3];
        f[4] = f1[0]; f[5] = f1[1]; f[6] = f1[2]; f[7] = f1[3];
    }

    float res[8];
    #pragma unroll
    for (int pp = 0; pp < 8; ++pp) {
        const int p = p0 + pp;
        const int Y = p >> 6, X = p & 63;
        float acc = f[pp];
        {   // g2 bilinear 32 -> 64
            float ry = fminf(fmaxf(0.5f * Y - 0.25f, 0.f), 31.f);
            float rx = fminf(fmaxf(0.5f * X - 0.25f, 0.f), 31.f);
            int y0 = (int)ry, x0 = (int)rx;
            int y1 = min(y0 + 1, 31), x1 = min(x0 + 1, 31);
            float wy = ry - (float)y0, wx = rx - (float)x0;
            acc += (gs[y0 * 32 + x0] * (1.f - wx) + gs[y0 * 32 + x1] * wx) * (1.f - wy)
                 + (gs[y1 * 32 + x0] * (1.f - wx) + gs[y1 * 32 + x1] * wx) * wy;
        }
        {   // g3 bilinear 16 -> 64
            float ry = fminf(fmaxf(0.25f * Y - 0.375f, 0.f), 15.f);
            float rx = fminf(fmaxf(0.25f * X - 0.375f, 0.f), 15.f);
            int y0 = (int)ry, x0 = (int)rx;
            int y1 = min(y0 + 1, 15), x1 = min(x0 + 1, 15);
            float wy = ry - (float)y0, wx = rx - (float)x0;
            acc += (gs[1024 + y0 * 16 + x0] * (1.f - wx) + gs[1024 + y0 * 16 + x1] * wx) * (1.f - wy)
                 + (gs[1024 + y1 * 16 + x0] * (1.f - wx) + gs[1024 + y1 * 16 + x1] * wx) * wy;
        }
        res[pp] = fmaxf(acc, 0.f);
    }
    float* o = out + 153600 + (size_t)bn * 4096 + p0;
    *(float4*)(o)     = *(float4*)&res[0];
    *(float4*)(o + 4) = *(float4*)&res[4];
}

// ---------- output projection, n-split x2: out = xb @ Wp + bp. grid 38 ----------
__global__ __launch_bounds__(256) void proj_out(
    const float* __restrict__ xb, const unsigned short* __restrict__ Wtp,
    const float* __restrict__ bp, float* __restrict__ out)
{
    const int t = threadIdx.x;
    const int wave = t >> 6, lane = t & 63;
    const int m16 = lane & 15, quad = lane >> 4;
    const int msub = (wave & 1) * 16;
    const int m0 = (blockIdx.x >> 1) * 32;
    const int nc0 = (blockIdx.x & 1) * 128 + (wave >> 1) * 64;

    const int arow = min(m0 + msub + m16, 599);
    float4v acc[4];
    proj_core4(xb + (size_t)arow * 256 + quad * 8, Wtp, nc0, m16, quad, acc);

    #pragma unroll
    for (int i = 0; i < 4; ++i) {
        const float bv = bp[nc0 + i * 16 + m16];
        #pragma unroll
        for (int r = 0; r < 4; ++r) {
            int m = m0 + msub + quad * 4 + r;
            if (m < 600)
                out[(size_t)m * 256 + nc0 + i * 16 + m16] = acc[i][r] + bv;
        }
    }
}

// ---------- launch ----------
extern "C" void kernel_launch(void* const* d_in, const int* in_sizes, int n_in,
                              void* d_out, int out_size, void* d_ws, size_t ws_size,
                              hipStream_t stream) {
    const float* query = (const float*)d_in[0];
    const float* key   = (const float*)d_in[1];
    const float* value = (const float*)d_in[2];
    const float* Wq = (const float*)d_in[5];
    const float* Wk = (const float*)d_in[6];
    const float* Wv = (const float*)d_in[7];
    const float* Wp = (const float*)d_in[8];
    const float* bp = (const float*)d_in[9];
    const float* W1 = (const float*)d_in[10];
    const float* b1 = (const float*)d_in[11];
    const float* W2 = (const float*)d_in[12];
    const float* b2 = (const float*)d_in[13];
    const float* W3 = (const float*)d_in[14];
    const float* b3 = (const float*)d_in[15];
    const float* Wm = (const float*)d_in[16];
    const float* bm = (const float*)d_in[17];
    float* out = (float*)d_out;

    char* ws = (char*)d_ws;
    unsigned short* wt = (unsigned short*)(ws);       // 4*65536 bf16 = 524,288 B
    bf16*  qb    = (bf16*) (ws + 524288);             // 600*256 bf16
    bf16*  kb    = (bf16*) (ws + 831488);             // 10752*256 bf16
    bf16*  vt    = (bf16*) (ws + 6336512);            // 512*5376 bf16
    float* f1dot = (float*)(ws + 11841536);           // 600*4096 fp32
    float* gf    = (float*)(ws + 21671936);           // 600*1280 fp32
    float* xbp   = (float*)(ws + 24743936);           // 42*600*256 fp32 = 25,804,800 B
    float* Sp    = (float*)(ws + 50548736);           // 42*4800 fp32
    float* xb    = (float*)(ws + 51355136);           // 600*256 fp32

    cast_wt<<<dim3(4, 4, 4), 256, 0, stream>>>(Wq, Wk, Wv, Wp, wt);

    proj_all<<<1382, 256, 0, stream>>>(query, key, value, wt,
        (unsigned short*)qb, (unsigned short*)kb, (unsigned short*)vt);

    attn_fused<<<1600, 512, 0, stream>>>(
        (const unsigned short*)qb, (const unsigned short*)kb, (const unsigned short*)vt,
        W1, b1, W2, b2, W3, b3, Wm, bm,
        f1dot, gf, xbp, Sp);

    mask_combine<<<dim3(600, 3), 256, 0, stream>>>(f1dot, gf, xbp, Sp, xb, out);

    proj_out<<<38, 256, 0, stream>>>(xb, (const unsigned short*)wt + 196608, bp, out);
}